// Round 11
// baseline (234.959 us; speedup 1.0000x reference)
//
#include <hip/hip_runtime.h>
#include <cmath>
#include <complex>
#include <algorithm>

#ifndef M_PI
#define M_PI 3.14159265358979323846
#endif

typedef _Float16 f16x8 __attribute__((ext_vector_type(8)));
typedef _Float16 f16x4 __attribute__((ext_vector_type(4)));
typedef __fp16 fp16x2 __attribute__((ext_vector_type(2)));
typedef float f32x4 __attribute__((ext_vector_type(4)));

#define CHUNK 2   /* filtfilt steps per thread (1024 threads x 2 = 2048) */

// ---------------- coefficient structs (passed by value as kernel args) ---------
struct FiltArg {
  double b0[3], b1[3], b2[3], a1[3], a2[3];
  double zi0[3], zi1[3];
};
struct CorArg { double CA[16 * 6]; };  // CA[i][j] = output at step i from unit state e_j
struct EigArg {
  double Pm[36], Pinv[36];   // eigenbasis of the single-step state matrix A
  double czi[6];             // Pinv · (zi vector)
  double lam_re[3], lam_im[3];   // λ_s = p_s^CHUNK
  double lami_re[3], lami_im[3]; // λ_s^{-1}
};
struct FirArg { float h[526]; };  // 25 leading zeros + 501-tap kaiser-sinc, *UP

// ---------------- host-side filter design (exact replica of reference) --------
static void design_sos(FiltArg& sa) {
  const int order = 6;
  const double wn = 0.5 / 50.0;
  const double fs = 2.0;
  double warped = 2.0 * fs * std::tan(M_PI * wn / fs);
  std::complex<double> p[6];
  for (int i = 0; i < order; i++) {
    int m = -order + 1 + 2 * i;                      // -5,-3,-1,1,3,5
    p[i] = -std::exp(std::complex<double>(0.0, M_PI * m / (2.0 * order)));
  }
  std::complex<double> prod1(1, 0);
  for (int i = 0; i < 6; i++) prod1 *= -p[i];
  double k = (1.0 / prod1).real();
  for (int i = 0; i < 6; i++) p[i] = warped / p[i];
  const double fs2 = 2.0 * fs;
  std::complex<double> num(1, 0), den(1, 0);
  for (int i = 0; i < 6; i++) { num *= fs2; den *= (fs2 - p[i]); }
  k *= (num / den).real();
  for (int i = 0; i < 6; i++) p[i] = (fs2 + p[i]) / (fs2 - p[i]);
  std::complex<double> pp[3]; int n = 0;
  for (int i = 0; i < 6; i++) if (p[i].imag() > 0) pp[n++] = p[i];
  std::stable_sort(pp, pp + 3,
    [](const std::complex<double>& A, const std::complex<double>& B) {
      return std::fabs(std::abs(A) - 1.0) > std::fabs(std::abs(B) - 1.0);
    });
  double sos[3][6];
  for (int s = 0; s < 3; s++) {
    double g = (s == 0) ? k : 1.0;
    sos[s][0] = g; sos[s][1] = -2.0 * g; sos[s][2] = g;
    sos[s][3] = 1.0; sos[s][4] = -2.0 * pp[s].real(); sos[s][5] = std::norm(pp[s]);
  }
  double scale = 1.0;
  for (int s = 0; s < 3; s++) {
    double b0 = sos[s][0], b1 = sos[s][1], b2 = sos[s][2];
    double a1 = sos[s][4], a2 = sos[s][5];
    double det = 1.0 + a1 + a2;                      // det of [[1+a1,-1],[a2,1]]
    double r0 = b1 - a1 * b0, r1 = b2 - a2 * b0;
    double z0 = (r0 + r1) / det;
    double z1 = ((1.0 + a1) * r1 - a2 * r0) / det;
    sa.b0[s] = b0; sa.b1[s] = b1; sa.b2[s] = b2; sa.a1[s] = a1; sa.a2[s] = a2;
    sa.zi0[s] = scale * z0; sa.zi1[s] = scale * z1;
    scale *= (b0 + b1 + b2) / (1.0 + a1 + a2);
  }
}

static double host_step(const FiltArg& c, double z[6], double v) {
  for (int s = 0; s < 3; s++) {
    double y = c.b0[s] * v + z[2 * s];
    z[2 * s]     = c.b1[s] * v - c.a1[s] * y + z[2 * s + 1];
    z[2 * s + 1] = c.b2[s] * v - c.a2[s] * y;
    v = y;
  }
  return v;
}

static void build_filt(FiltArg& c, CorArg& co) {
  design_sos(c);
  for (int j = 0; j < 6; j++) {
    double z[6] = {0, 0, 0, 0, 0, 0};
    z[j] = 1.0;
    for (int i = 0; i < 16; i++) co.CA[i * 6 + j] = host_step(c, z, 0.0);
  }
}

static void build_eig(const FiltArg& c, EigArg& e) {
  double Pr[36];
  for (int s = 0; s < 3; s++) {
    double a1 = c.a1[s], a2 = c.a2[s];
    std::complex<double> disc = std::sqrt(std::complex<double>(a1 * a1 - 4.0 * a2, 0.0));
    std::complex<double> p = (-a1 + disc) / 2.0;
    if (p.imag() < 0) p = std::conj(p);
    std::complex<double> v[6] = {0, 0, 0, 0, 0, 0};
    v[2 * s] = 1.0;
    v[2 * s + 1] = a1 + p;
    std::complex<double> y = 1.0;
    for (int j = s + 1; j < 3; j++) {
      double b0j = c.b0[j], b1j = c.b1[j], b2j = c.b2[j];
      double a1j = c.a1[j], a2j = c.a2[j];
      std::complex<double> det = p * p + a1j * p + a2j;
      std::complex<double> r0 = (b1j - a1j * b0j) * y;
      std::complex<double> r1 = (b2j - a2j * b0j) * y;
      std::complex<double> z0 = (p * r0 + r1) / det;
      std::complex<double> z1 = ((p + a1j) * r1 - a2j * r0) / det;
      v[2 * j] = z0; v[2 * j + 1] = z1;
      y = b0j * y + z0;
    }
    for (int i = 0; i < 6; i++) {
      Pr[i * 6 + 2 * s]     = v[i].real();
      Pr[i * 6 + 2 * s + 1] = v[i].imag();
    }
    std::complex<double> lam = std::pow(p, CHUNK);
    e.lam_re[s] = lam.real(); e.lam_im[s] = lam.imag();
    std::complex<double> li = 1.0 / lam;
    e.lami_re[s] = li.real(); e.lami_im[s] = li.imag();
  }
  for (int i = 0; i < 36; i++) e.Pm[i] = Pr[i];
  double M[6][12];
  for (int i = 0; i < 6; i++)
    for (int j = 0; j < 6; j++) { M[i][j] = Pr[i * 6 + j]; M[i][6 + j] = (i == j) ? 1.0 : 0.0; }
  for (int col = 0; col < 6; col++) {
    int piv = col;
    for (int i = col + 1; i < 6; i++)
      if (std::fabs(M[i][col]) > std::fabs(M[piv][col])) piv = i;
    if (piv != col) for (int j = 0; j < 12; j++) std::swap(M[col][j], M[piv][j]);
    double d = M[col][col];
    for (int j = 0; j < 12; j++) M[col][j] /= d;
    for (int i = 0; i < 6; i++) if (i != col) {
      double f = M[i][col];
      for (int j = 0; j < 12; j++) M[i][j] -= f * M[col][j];
    }
  }
  for (int i = 0; i < 6; i++)
    for (int j = 0; j < 6; j++) e.Pinv[i * 6 + j] = M[i][6 + j];
  double zv[6];
  for (int s = 0; s < 3; s++) { zv[2 * s] = c.zi0[s]; zv[2 * s + 1] = c.zi1[s]; }
  for (int i = 0; i < 6; i++) {
    double sum = 0.0;
    for (int j = 0; j < 6; j++) sum += e.Pinv[i * 6 + j] * zv[j];
    e.czi[i] = sum;
  }
}

static double bessel_i0(double x) {
  double s = 1.0, t = 1.0;
  for (int k = 1; k < 64; k++) {
    double u = x / (2.0 * k);
    t *= u * u; s += t;
    if (t < 1e-18 * s) break;
  }
  return s;
}

static void design_fir(FirArg& fa) {
  double h[501];
  const double fc = 1.0 / 25.0;
  double denom = bessel_i0(5.0);
  double sum = 0.0;
  for (int nn = 0; nn < 501; nn++) {
    double m = nn - 250.0;
    double xx = fc * m;
    double snc = (nn == 250) ? 1.0 : std::sin(M_PI * xx) / (M_PI * xx);
    double r = (2.0 * nn) / 500.0 - 1.0;
    double w = bessel_i0(5.0 * std::sqrt(std::max(0.0, 1.0 - r * r))) / denom;
    h[nn] = fc * snc * w; sum += h[nn];
  }
  for (int nn = 0; nn < 25; nn++) fa.h[nn] = 0.0f;          // n_pre_pad = 25
  for (int nn = 0; nn < 501; nn++) fa.h[25 + nn] = (float)(h[nn] / sum * 16.0);
}

// ---------------- device helpers ----------------
__device__ inline double waveReduceSum(double v) {
  #pragma unroll
  for (int off = 32; off > 0; off >>= 1) v += __shfl_down(v, off, 64);
  return v;
}

__device__ inline void cpowf_int(float br, float bi, int n, float& rr_, float& ri_) {
  float rr = 1.f, ri = 0.f;
  while (n) {
    if (n & 1) { float t = rr * br - ri * bi; ri = rr * bi + ri * br; rr = t; }
    float t2 = br * br - bi * bi; bi = 2.f * br * bi; br = t2;
    n >>= 1;
  }
  rr_ = rr; ri_ = ri;
}

// ---------------- kernel 1: chansel + filtfilt + resample + norm (fused, f32) -
// Blocks [0,640): one row each, 1024 threads, CHUNK=2 steps/thread (serial IIR
// chain halved again vs r10; 16 waves/block). λ^±gk powers hoisted (computed
// once, used by both fwd/bwd scans). Blocks [640,660): PE table; block 659
// zeroes out.
#define XR(t) xr[(t) + ((t) >> 5)]
#define YFS(t) yfs[(t) + ((t) >> 5)]
__global__ __launch_bounds__(1024) void k_filt_resamp(const float* __restrict__ xin,
                                                      float* __restrict__ xn,
                                                      float* __restrict__ pe,
                                                      float* __restrict__ out,
                                                      FiltArg c, CorArg co, EigArg eg,
                                                      FirArg fa) {
  int bid = blockIdx.x;
  int gk = threadIdx.x;           // chunk id 0..1023
  if (bid >= 640) {               // ---- PE-table + out-zero blocks ----
    int i = (bid - 640) * 1024 + gk; // [0, 20480)
    int t = i >> 4, d = i & 15, j2 = d >> 1;
    double div = exp(-((double)(2 * j2)) * 0.5756462732485114); // ln(10000)/16
    double a = (double)t * div;
    pe[i] = (float)((d & 1) ? cos(a) : sin(a));
    if (bid == 659 && gk < 64) out[gk] = 0.f;
    return;
  }
  int r = (bid & 7) * 80 + (bid >> 3);   // bijective [0,640): XCD-local batches
  __shared__ float xd[2000];      // demeaned row, later reused for final output
  __shared__ float xr[2178];      // extended input seq (padded)
  __shared__ float yfs[2178];     // corrected forward output (padded, f32)
  __shared__ float hl[526];
  __shared__ float wtot[3][16][2]; // per-wave scan totals per section
  __shared__ double red[32];
  int lane = gk & 63;
  int wv = gk >> 6;               // 0..15
  int bb = r / 10, cc = r % 10;
  const int ch[10] = {126, 125, 48, 112, 67, 93, 10, 61, 39, 108};
  const float* xb = xin + (size_t)bb * 128 * 2000;

  for (int i = gk; i < 526; i += 1024) hl[i] = fa.h[i];
  // demeaned row into LDS (identical arithmetic to the original chansel)
  for (int t = gk; t < 2000; t += 1024) {
    float own = 0.f, ssum = 0.f;
    #pragma unroll
    for (int c2 = 0; c2 < 10; c2++) {
      float vv = xb[ch[c2] * 2000 + t];
      ssum += vv;
      if (c2 == cc) own = vv;
    }
    xd[t] = own - ssum * 0.1f;
  }
  __syncthreads();

  float x0f = xd[0], xlf = xd[1999];
  for (int t = gk; t < 2048; t += 1024) {
    float v;
    if (t < 21)        v = 2.f * x0f - xd[21 - t];
    else if (t < 2021) v = xd[t - 21];
    else if (t < 2042) v = 2.f * xlf - xd[4019 - t];
    else               v = 0.f;
    XR(t) = v;
  }
  __syncthreads();

  float b0[3], b1[3], b2[3], a1[3], a2[3];
  #pragma unroll
  for (int s = 0; s < 3; s++) {
    b0[s] = (float)c.b0[s]; b1[s] = (float)c.b1[s]; b2[s] = (float)c.b2[s];
    a1[s] = (float)c.a1[s]; a2[s] = (float)c.a2[s];
  }
  // hoisted λ^gk and λ^-gk per section (used by BOTH eigscan calls)
  float lamk_re[3], lamk_im[3], lamik_re[3], lamik_im[3];
  #pragma unroll
  for (int s3 = 0; s3 < 3; s3++) {
    cpowf_int((float)eg.lam_re[s3], (float)eg.lam_im[s3], gk, lamk_re[s3], lamk_im[s3]);
    cpowf_int((float)eg.lami_re[s3], (float)eg.lami_im[s3], gk, lamik_re[s3], lamik_im[s3]);
  }

  auto step = [&](float* z, float v) -> float {
    #pragma unroll
    for (int s = 0; s < 3; s++) {
      float y = b0[s] * v + z[2 * s];
      z[2 * s]     = b1[s] * v - a1[s] * y + z[2 * s + 1];
      z[2 * s + 1] = b2[s] * v - a2[s] * y;
      v = y;
    }
    return v;
  };

  auto eigscan = [&](float seed, const float* F, float* zst) {
    float G[6];
    #pragma unroll
    for (int i = 0; i < 6; i++) {
      float s = 0.f;
      #pragma unroll
      for (int j = 0; j < 6; j++) s += (float)eg.Pinv[i * 6 + j] * F[j];
      G[i] = s;
    }
    float tre[3], tim[3], sre[3], sim[3];
    #pragma unroll
    for (int s3 = 0; s3 < 3; s3++) {
      float gre = G[2 * s3], gim = -G[2 * s3 + 1];
      float mre = lamik_re[s3], mim = lamik_im[s3];    // λ^{-gk} (hoisted)
      tre[s3] = mre * gre - mim * gim;
      tim[s3] = mre * gim + mim * gre;
      float pr = tre[s3], pi = tim[s3];
      #pragma unroll
      for (int off = 1; off < 64; off <<= 1) {
        float ore = __shfl_up(pr, off, 64);
        float oim = __shfl_up(pi, off, 64);
        pr += (lane >= off) ? ore : 0.f;
        pi += (lane >= off) ? oim : 0.f;
      }
      sre[s3] = pr; sim[s3] = pi;
      if (lane == 63) { wtot[s3][wv][0] = pr; wtot[s3][wv][1] = pi; }
    }
    __syncthreads();
    float coord[6];
    #pragma unroll
    for (int s3 = 0; s3 < 3; s3++) {
      float inc_re = sre[s3], inc_im = sim[s3];
      for (int w = 0; w < wv; w++) {      // wave-uniform trip count
        inc_re += wtot[s3][w][0];
        inc_im += wtot[s3][w][1];
      }
      float Sre = inc_re - tre[s3], Sim = inc_im - tim[s3];
      float c0re = seed * (float)eg.czi[2 * s3];
      float c0im = -seed * (float)eg.czi[2 * s3 + 1];
      float lkre = lamk_re[s3], lkim = lamk_im[s3];    // λ^{gk} (hoisted)
      float lamire = (float)eg.lami_re[s3], lamiim = (float)eg.lami_im[s3];
      float lm1re = lkre * lamire - lkim * lamiim;     // λ^{gk-1}
      float lm1im = lkre * lamiim + lkim * lamire;
      if (gk == 0) { lm1re = 0.f; lm1im = 0.f; }
      float cre = lkre * c0re - lkim * c0im + lm1re * Sre - lm1im * Sim;
      float cim = lkre * c0im + lkim * c0re + lm1re * Sim + lm1im * Sre;
      coord[2 * s3] = cre;
      coord[2 * s3 + 1] = -cim;
    }
    #pragma unroll
    for (int i = 0; i < 6; i++) {
      float s = 0.f;
      #pragma unroll
      for (int j = 0; j < 6; j++) s += (float)eg.Pm[i * 6 + j] * coord[j];
      zst[i] = s;
    }
  };

  int t0 = gk * CHUNK;
  float z[6], yreg[CHUNK], zst[6];

  #pragma unroll
  for (int i = 0; i < 6; i++) z[i] = 0.f;
  #pragma unroll
  for (int i = 0; i < CHUNK; i++) yreg[i] = step(z, XR(t0 + i));
  eigscan(XR(0), z, zst);
  #pragma unroll
  for (int i = 0; i < CHUNK; i++) {
    float corr = 0.f;
    #pragma unroll
    for (int j = 0; j < 6; j++) corr += (float)co.CA[i * 6 + j] * zst[j];
    YFS(t0 + i) = yreg[i] + corr;
  }
  __syncthreads();

  auto rin = [&](int j) -> float { return (j <= 2041) ? YFS(2041 - j) : 0.f; };
  float seedB = YFS(2041);
  #pragma unroll
  for (int i = 0; i < 6; i++) z[i] = 0.f;
  #pragma unroll
  for (int i = 0; i < CHUNK; i++) yreg[i] = step(z, rin(t0 + i));
  eigscan(seedB, z, zst);
  #pragma unroll
  for (int i = 0; i < CHUNK; i++) {
    int j = t0 + i;
    if (j >= 21 && j <= 2020) {
      float corr = 0.f;
      #pragma unroll
      for (int jj = 0; jj < 6; jj++) corr += (float)co.CA[i * 6 + jj] * zst[jj];
      xd[2020 - j] = yreg[i] + corr;        // reversed + trimmed -> LDS
    }
  }
  __syncthreads();

  // ---- polyphase resample + tanh + per-row normalize (from LDS xd) ----
  float vals[2];
  #pragma unroll
  for (int kk = 0; kk < 2; kk++) {
    int o = gk + kk * 1024;                   // 1280 outputs per row
    vals[kk] = 0.f;
    if (o < 1280) {
      int P = 25 * (o + 11);
      int phase = P & 15;
      float acc = 0.f;
      for (int m = phase; m <= 525; m += 16) {
        int idx = (P - m) >> 4;
        if (idx >= 0 && idx < 2000) acc += hl[m] * xd[idx];
      }
      vals[kk] = tanhf(acc);
    }
  }
  double s = 0.0, ss = 0.0;
  #pragma unroll
  for (int kk = 0; kk < 2; kk++) {
    s += (double)vals[kk]; ss += (double)vals[kk] * (double)vals[kk];
  }
  s = waveReduceSum(s); ss = waveReduceSum(ss);
  if (lane == 0) { red[wv] = s; red[16 + wv] = ss; }
  __syncthreads();
  double S = 0.0, SS = 0.0;
  #pragma unroll
  for (int w = 0; w < 16; w++) { S += red[w]; SS += red[16 + w]; }
  double mean = S / 1280.0;
  double var = (SS - 1280.0 * mean * mean) / 1279.0;
  double sd = fmax(sqrt(fmax(var, 0.0)), 1e-6);
  float fmean = (float)mean, finv = (float)(1.0 / sd);
  #pragma unroll
  for (int kk = 0; kk < 2; kk++) {
    int o = gk + kk * 1024;
    if (o < 1280)
      xn[(size_t)r * 1280 + o] = (vals[kk] - fmean) * finv;
  }
}

// ---------------- kernel 2: conv1d + relu + LN + PE + QKV (Q,K,V emitted f16) -
__global__ __launch_bounds__(256) void k_conv_ln_pe_qkv(const float* __restrict__ xn,
    const float* __restrict__ cw, const float* __restrict__ cb,
    const float* __restrict__ g0, const float* __restrict__ bt0,
    const float* __restrict__ wqkv, const float* __restrict__ bqkv,
    const float* __restrict__ pe,
    float* __restrict__ x0, _Float16* __restrict__ Qh,
    _Float16* __restrict__ Kp, _Float16* __restrict__ Vt_g) {
  __shared__ float w[480], bias[16], gg[16], gb[16];
  __shared__ float wq[768], bq[48];
  for (int i = threadIdx.x; i < 480; i += 256) w[i] = cw[i];
  for (int i = threadIdx.x; i < 768; i += 256) wq[i] = wqkv[i];
  if (threadIdx.x < 16) {
    bias[threadIdx.x] = cb[threadIdx.x];
    gg[threadIdx.x] = g0[threadIdx.x];
    gb[threadIdx.x] = bt0[threadIdx.x];
  }
  if (threadIdx.x < 48) bq[threadIdx.x] = bqkv[threadIdx.x];
  __syncthreads();
  int idx = blockIdx.x * 256 + threadIdx.x;
  int b = idx / 1280, t = idx % 1280;
  const float* xb = xn + (size_t)b * 10 * 1280;
  float in[10][3];
  #pragma unroll
  for (int i = 0; i < 10; i++)
    #pragma unroll
    for (int k = 0; k < 3; k++) {
      int tt = t - 1 + k;
      in[i][k] = (tt >= 0 && tt < 1280) ? xb[i * 1280 + tt] : 0.f;
    }
  float o[16];
  #pragma unroll
  for (int oc = 0; oc < 16; oc++) {
    float a = bias[oc];
    #pragma unroll
    for (int i = 0; i < 10; i++)
      #pragma unroll
      for (int k = 0; k < 3; k++) a += in[i][k] * w[oc * 30 + i * 3 + k];
    o[oc] = fmaxf(a, 0.f);
  }
  float mu = 0.f;
  #pragma unroll
  for (int d = 0; d < 16; d++) mu += o[d];
  mu *= (1.f / 16.f);
  float var = 0.f;
  #pragma unroll
  for (int d = 0; d < 16; d++) { float dd = o[d] - mu; var += dd * dd; }
  var *= (1.f / 16.f);
  float inv = 1.f / sqrtf(var + 1e-5f);
  float xv[16];
  float* outp = x0 + (size_t)idx * 16;
  const float* pep = pe + t * 16;
  #pragma unroll
  for (int d = 0; d < 16; d++) {
    xv[d] = (o[d] - mu) * inv * gg[d] + gb[d] + pep[d];
    outp[d] = xv[d];
  }
  _Float16* qh = Qh + (size_t)idx * 16;
  #pragma unroll
  for (int j = 0; j < 16; j++) {
    float a = bq[j];
    #pragma unroll
    for (int d = 0; d < 16; d++) a += xv[d] * wq[j * 16 + d];
    qh[j] = (_Float16)(0.36067376f * a);   // 0.25 * log2(e)
  }
  {
    _Float16* kp = Kp + (size_t)idx * 16;
    #pragma unroll
    for (int j = 0; j < 16; j++) {
      float a = bq[16 + j];
      #pragma unroll
      for (int d = 0; d < 16; d++) a += xv[d] * wq[(16 + j) * 16 + d];
      kp[j] = (_Float16)a;
    }
  }
  {
    _Float16* vt = Vt_g + (size_t)b * 16 * 1280 + t;
    #pragma unroll
    for (int j = 0; j < 16; j++) {
      float a = bq[32 + j];
      #pragma unroll
      for (int d = 0; d < 16; d++) a += xv[d] * wq[(32 + j) * 16 + d];
      vt[j * 1280] = (_Float16)a;
    }
  }
}

// ---------------- kernel 3: MFMA attention + combine + pool (fused) -----------
// r9 zero-shuffle configuration (verified): key-relabeled PV (P-slot/V-slot
// agree per lane), MFMA-ones denominator, XCD swizzle, 128-key dbuf tiles.
#define SHIFT2 17.3123404907f   /* 12 * log2(e) */
__global__ __launch_bounds__(256) void k_attn_combine(const _Float16* __restrict__ Qh,
    const _Float16* __restrict__ Kp, const _Float16* __restrict__ Vt_g,
    const float* __restrict__ x0,
    const float* __restrict__ wo, const float* __restrict__ bo,
    const float* __restrict__ w1, const float* __restrict__ b1,
    const float* __restrict__ w2, const float* __restrict__ b2,
    const float* __restrict__ g1, const float* __restrict__ bb1,
    const float* __restrict__ g2, const float* __restrict__ bb2,
    const float* __restrict__ wfc, const float* __restrict__ bfc,
    float* __restrict__ out) {
  __shared__ __align__(16) _Float16 Ks[2][128 * 16];   // [buf][key][d]
  __shared__ __align__(16) _Float16 Vt[2][16 * 136];   // [buf][d][key+8pad]
  __shared__ float Aly[64][17];                        // normalized attn rows
  __shared__ float swo[256], sw1[512], sw2[512];
  __shared__ float sbo[16], sb1[32], sb2[16], sg1[16], sbb1[16], sg2[16], sbb2[16];
  __shared__ float swf[16];
  int tid = threadIdx.x;
  // XCD swizzle: bid&7 = XCD (round-robin). Keep a batch on one XCD.
  int bid = blockIdx.x;
  int jj  = bid >> 3;
  int b   = (bid & 7) + 8 * (jj & 7);   // [0,64)
  int rg  = jj >> 3;                    // [0,20)
  int wv = tid >> 6;
  int lane = tid & 63;
  int col = lane & 15;
  int quad = lane >> 4;
  size_t base = (size_t)b * 1280;
  int row0 = rg * 64 + wv * 16;

  // stage combine weights (consumed after a barrier)
  swo[tid] = wo[tid];
  for (int i = tid; i < 512; i += 256) { sw1[i] = w1[i]; sw2[i] = w2[i]; }
  if (tid < 16) {
    sbo[tid] = bo[tid]; sb2[tid] = b2[tid];
    sg1[tid] = g1[tid]; sbb1[tid] = bb1[tid];
    sg2[tid] = g2[tid]; sbb2[tid] = bb2[tid];
    swf[tid] = wfc[tid];
  }
  if (tid < 32) sb1[tid] = b1[tid];

  // Q fragment (B operand, k=quad*8+j; quads 2-3 zero == K dims 16..31 zero)
  f16x8 qf;
  #pragma unroll
  for (int j = 0; j < 8; j++) qf[j] = (_Float16)0.f;
  if (quad < 2)
    qf = *(const f16x8*)(Qh + (base + row0 + col) * 16 + quad * 8);

  f16x8 ones;
  #pragma unroll
  for (int j = 0; j < 8; j++) ones[j] = (_Float16)1.f;

  const _Float16* kp_b = Kp + base * 16;
  const _Float16* vt_b = Vt_g + (size_t)b * 16 * 1280;

  // staging roles: Ks by all 256 (16B each), Vt by all 256 (16B each)
  int srow = tid >> 1, shalf = tid & 1;      // Ks: key row, 8-f16 half
  int sd = tid >> 4, sseg = tid & 15;        // Vt: d row, 8-key segment

  // prologue: tile 0 -> buf 0
  {
    f16x8 kreg = *(const f16x8*)(kp_b + (size_t)srow * 16 + shalf * 8);
    f16x8 vreg = *(const f16x8*)(vt_b + (size_t)sd * 1280 + sseg * 8);
    *(f16x8*)&Ks[0][srow * 16 + shalf * 8] = kreg;
    *(f16x8*)&Vt[0][sd * 136 + sseg * 8] = vreg;
  }

  f32x4 oacc = {0.f, 0.f, 0.f, 0.f};
  f32x4 lacc = {0.f, 0.f, 0.f, 0.f};

  union U32H2 { fp16x2 h; unsigned int u; };
  union PFU { unsigned int u[4]; f16x8 v; };
  union VFU { unsigned long long d[2]; f16x8 v; };

  for (int s = 0; s < 10; s++) {
    int cur = s & 1;
    f16x8 kreg, vreg;
    if (s < 9) {                     // issue next-tile global loads early
      kreg = *(const f16x8*)(kp_b + (size_t)((s + 1) * 128 + srow) * 16 + shalf * 8);
      vreg = *(const f16x8*)(vt_b + (size_t)sd * 1280 + (s + 1) * 128 + sseg * 8);
    }
    __syncthreads();                 // buf[cur] staging complete
    const _Float16* ks = &Ks[cur][0];
    const _Float16* vt = &Vt[cur][0];

    // Phase A: QK + exp for all 8 sub-tiles (max ILP across exp chains)
    unsigned int pp[8][2];
    #pragma unroll
    for (int st = 0; st < 8; st++) {
      f16x8 af;
      #pragma unroll
      for (int j = 0; j < 8; j++) af[j] = (_Float16)0.f;
      if (quad < 2)
        af = *(const f16x8*)&ks[(st * 16 + col) * 16 + quad * 8];
      f32x4 sf = {-SHIFT2, -SHIFT2, -SHIFT2, -SHIFT2};
      sf = __builtin_amdgcn_mfma_f32_16x16x32_f16(af, qf, sf, 0, 0, 0);
      float e0 = __builtin_amdgcn_exp2f(sf[0]);
      float e1 = __builtin_amdgcn_exp2f(sf[1]);
      float e2 = __builtin_amdgcn_exp2f(sf[2]);
      float e3 = __builtin_amdgcn_exp2f(sf[3]);
      U32H2 t0, t1;
      t0.h = __builtin_amdgcn_cvt_pkrtz(e0, e1);
      t1.h = __builtin_amdgcn_cvt_pkrtz(e2, e3);
      pp[st][0] = t0.u;              // keys st*16 + quad*4 + {0,1}, q=col
      pp[st][1] = t1.u;              // keys st*16 + quad*4 + {2,3}
    }

    // Phase B: zero-shuffle PV. A-slot 8*quad+j holds the lane's own exp
    // values (keys c*32+{4q..4q+3, 16+4q..16+4q+3}); V read at same keys.
    #pragma unroll
    for (int c = 0; c < 4; c++) {
      PFU pu;
      pu.u[0] = pp[2 * c][0];          // keys c*32 + 4*quad + {0,1}
      pu.u[1] = pp[2 * c][1];          // keys c*32 + 4*quad + {2,3}
      pu.u[2] = pp[2 * c + 1][0];      // keys c*32 + 16 + 4*quad + {0,1}
      pu.u[3] = pp[2 * c + 1][1];      // keys c*32 + 16 + 4*quad + {2,3}
      f16x8 pf = pu.v;
      VFU vu;
      vu.d[0] = *(const unsigned long long*)&vt[col * 136 + c * 32 + quad * 4];
      vu.d[1] = *(const unsigned long long*)&vt[col * 136 + c * 32 + 16 + quad * 4];
      f16x8 vf = vu.v;
      oacc = __builtin_amdgcn_mfma_f32_16x16x32_f16(pf, vf, oacc, 0, 0, 0);
      lacc = __builtin_amdgcn_mfma_f32_16x16x32_f16(pf, ones, lacc, 0, 0, 0);
    }
    if (s < 9) {                     // write next tile to the other buffer
      *(f16x8*)&Ks[cur ^ 1][srow * 16 + shalf * 8] = kreg;
      *(f16x8*)&Vt[cur ^ 1][sd * 136 + sseg * 8] = vreg;
    }
  }

  // lacc[r] = l for q-row quad*4+r (identical across cols) -> normalize here
  #pragma unroll
  for (int r = 0; r < 4; r++)
    Aly[wv * 16 + quad * 4 + r][col] = oacc[r] / lacc[r];
  __syncthreads();

  // ---- epilogue: wave 0, one thread per row ----
  if (tid < 64) {
    int grow = rg * 64 + tid;                 // row within batch
    size_t goff = (base + grow) * 16;
    float a[16];
    #pragma unroll
    for (int d = 0; d < 16; d++) a[d] = Aly[tid][d];
    float h[16];
    const float* xr = x0 + goff;
    #pragma unroll
    for (int d = 0; d < 16; d++) {
      float o = sbo[d];
      #pragma unroll
      for (int e = 0; e < 16; e++) o += a[e] * swo[d * 16 + e];
      h[d] = xr[d] + o;
    }
    float mu = 0.f;
    #pragma unroll
    for (int d = 0; d < 16; d++) mu += h[d];
    mu *= (1.f / 16.f);
    float var = 0.f;
    #pragma unroll
    for (int d = 0; d < 16; d++) { float dd = h[d] - mu; var += dd * dd; }
    var *= (1.f / 16.f);
    float inv = 1.f / sqrtf(var + 1e-5f);
    float x1[16];
    #pragma unroll
    for (int d = 0; d < 16; d++) x1[d] = (h[d] - mu) * inv * sg1[d] + sbb1[d];
    float t1[32];
    #pragma unroll
    for (int j = 0; j < 32; j++) {
      float u = sb1[j];
      #pragma unroll
      for (int d = 0; d < 16; d++) u += x1[d] * sw1[j * 16 + d];
      t1[j] = fmaxf(u, 0.f);
    }
    float h2[16];
    #pragma unroll
    for (int d = 0; d < 16; d++) {
      float u = sb2[d];
      #pragma unroll
      for (int j = 0; j < 32; j++) u += t1[j] * sw2[d * 32 + j];
      h2[d] = x1[d] + u;
    }
    mu = 0.f;
    #pragma unroll
    for (int d = 0; d < 16; d++) mu += h2[d];
    mu *= (1.f / 16.f);
    var = 0.f;
    #pragma unroll
    for (int d = 0; d < 16; d++) { float dd = h2[d] - mu; var += dd * dd; }
    var *= (1.f / 16.f);
    inv = 1.f / sqrtf(var + 1e-5f);
    float pv = 0.f;
    #pragma unroll
    for (int d = 0; d < 16; d++)
      pv += ((h2[d] - mu) * inv * sg2[d] + sbb2[d]) * swf[d];
    double part = waveReduceSum((double)pv);
    if (tid == 0) {
      float add = (float)(part / 1280.0);
      if (rg == 0) add += bfc[0];           // once per batch (swizzled ids!)
      atomicAdd(&out[b], add);
    }
  }
}

// ---------------- launch ------------------------------------------------------
extern "C" void kernel_launch(void* const* d_in, const int* in_sizes, int n_in,
                              void* d_out, int out_size, void* d_ws, size_t ws_size,
                              hipStream_t stream) {
  const float* x    = (const float*)d_in[0];
  const float* cw   = (const float*)d_in[1];
  const float* cb   = (const float*)d_in[2];
  const float* g0   = (const float*)d_in[3];
  const float* bt0  = (const float*)d_in[4];
  const float* wqkv = (const float*)d_in[5];
  const float* bqkv = (const float*)d_in[6];
  const float* wo   = (const float*)d_in[7];
  const float* bo   = (const float*)d_in[8];
  const float* w1   = (const float*)d_in[9];
  const float* b1   = (const float*)d_in[10];
  const float* w2   = (const float*)d_in[11];
  const float* b2   = (const float*)d_in[12];
  const float* g1   = (const float*)d_in[13];
  const float* bb1  = (const float*)d_in[14];
  const float* g2   = (const float*)d_in[15];
  const float* bb2  = (const float*)d_in[16];
  const float* wfc  = (const float*)d_in[17];
  const float* bfc  = (const float*)d_in[18];
  float* out = (float*)d_out;

  float* ws = (float*)d_ws;
  float* xs = ws;                       // (dead; layout kept stable)
  float* y1 = xs + 1280000;             // spacer (dead)
  float* xn = y1 + 1306880;             // 640*1280   =   819,200
  float* x0 = xn + 819200;              // 64*1280*16 = 1,310,720
  _Float16* Qh   = (_Float16*)(x0 + 1310720);     // 64*1280*16 f16 = 655,360 floats
  _Float16* Kp   = (_Float16*)(x0 + 1310720 + 655360);
  _Float16* Vt_g = (_Float16*)(x0 + 1310720 + 2 * 655360);
  float* pe = x0 + 1310720 + 3 * 655360;          // 1280*16 = 20,480 (total ~27 MB)

  FiltArg fc; CorArg co; EigArg eg; FirArg fa;
  build_filt(fc, co);
  build_eig(fc, eg);
  design_fir(fa);

  k_filt_resamp<<<660, 1024, 0, stream>>>(x, xn, pe, out, fc, co, eg, fa);
  k_conv_ln_pe_qkv<<<320, 256, 0, stream>>>(xn, cw, cb, g0, bt0, wqkv, bqkv,
                                            pe, x0, Qh, Kp, Vt_g);
  k_attn_combine<<<1280, 256, 0, stream>>>(Qh, Kp, Vt_g, x0, wo, bo, w1, b1,
                                           w2, b2, g1, bb1, g2, bb2, wfc, bfc,
                                           out);
}

// Round 12
// 202.470 us; speedup vs baseline: 1.1605x; 1.1605x over previous
//
#include <hip/hip_runtime.h>
#include <cmath>
#include <complex>
#include <algorithm>

#ifndef M_PI
#define M_PI 3.14159265358979323846
#endif

typedef _Float16 f16x8 __attribute__((ext_vector_type(8)));
typedef _Float16 f16x4 __attribute__((ext_vector_type(4)));
typedef __fp16 fp16x2 __attribute__((ext_vector_type(2)));
typedef float f32x4 __attribute__((ext_vector_type(4)));

#define CHUNK 4   /* filtfilt steps per thread (512 threads x 4 = 2048) */

// ---------------- coefficient structs (passed by value as kernel args) ---------
struct FiltArg {
  double b0[3], b1[3], b2[3], a1[3], a2[3];
  double zi0[3], zi1[3];
};
struct CorArg { double CA[16 * 6]; };  // CA[i][j] = output at step i from unit state e_j
struct EigArg {
  double Pm[36], Pinv[36];   // eigenbasis of the single-step state matrix A
  double czi[6];             // Pinv · (zi vector)
  double lam_re[3], lam_im[3];   // λ_s = p_s^CHUNK
  double lami_re[3], lami_im[3]; // λ_s^{-1}
};
struct FirArg { float h[526]; };  // 25 leading zeros + 501-tap kaiser-sinc, *UP

// ---------------- host-side filter design (exact replica of reference) --------
static void design_sos(FiltArg& sa) {
  const int order = 6;
  const double wn = 0.5 / 50.0;
  const double fs = 2.0;
  double warped = 2.0 * fs * std::tan(M_PI * wn / fs);
  std::complex<double> p[6];
  for (int i = 0; i < order; i++) {
    int m = -order + 1 + 2 * i;                      // -5,-3,-1,1,3,5
    p[i] = -std::exp(std::complex<double>(0.0, M_PI * m / (2.0 * order)));
  }
  std::complex<double> prod1(1, 0);
  for (int i = 0; i < 6; i++) prod1 *= -p[i];
  double k = (1.0 / prod1).real();
  for (int i = 0; i < 6; i++) p[i] = warped / p[i];
  const double fs2 = 2.0 * fs;
  std::complex<double> num(1, 0), den(1, 0);
  for (int i = 0; i < 6; i++) { num *= fs2; den *= (fs2 - p[i]); }
  k *= (num / den).real();
  for (int i = 0; i < 6; i++) p[i] = (fs2 + p[i]) / (fs2 - p[i]);
  std::complex<double> pp[3]; int n = 0;
  for (int i = 0; i < 6; i++) if (p[i].imag() > 0) pp[n++] = p[i];
  std::stable_sort(pp, pp + 3,
    [](const std::complex<double>& A, const std::complex<double>& B) {
      return std::fabs(std::abs(A) - 1.0) > std::fabs(std::abs(B) - 1.0);
    });
  double sos[3][6];
  for (int s = 0; s < 3; s++) {
    double g = (s == 0) ? k : 1.0;
    sos[s][0] = g; sos[s][1] = -2.0 * g; sos[s][2] = g;
    sos[s][3] = 1.0; sos[s][4] = -2.0 * pp[s].real(); sos[s][5] = std::norm(pp[s]);
  }
  double scale = 1.0;
  for (int s = 0; s < 3; s++) {
    double b0 = sos[s][0], b1 = sos[s][1], b2 = sos[s][2];
    double a1 = sos[s][4], a2 = sos[s][5];
    double det = 1.0 + a1 + a2;                      // det of [[1+a1,-1],[a2,1]]
    double r0 = b1 - a1 * b0, r1 = b2 - a2 * b0;
    double z0 = (r0 + r1) / det;
    double z1 = ((1.0 + a1) * r1 - a2 * r0) / det;
    sa.b0[s] = b0; sa.b1[s] = b1; sa.b2[s] = b2; sa.a1[s] = a1; sa.a2[s] = a2;
    sa.zi0[s] = scale * z0; sa.zi1[s] = scale * z1;
    scale *= (b0 + b1 + b2) / (1.0 + a1 + a2);
  }
}

static double host_step(const FiltArg& c, double z[6], double v) {
  for (int s = 0; s < 3; s++) {
    double y = c.b0[s] * v + z[2 * s];
    z[2 * s]     = c.b1[s] * v - c.a1[s] * y + z[2 * s + 1];
    z[2 * s + 1] = c.b2[s] * v - c.a2[s] * y;
    v = y;
  }
  return v;
}

static void build_filt(FiltArg& c, CorArg& co) {
  design_sos(c);
  for (int j = 0; j < 6; j++) {
    double z[6] = {0, 0, 0, 0, 0, 0};
    z[j] = 1.0;
    for (int i = 0; i < 16; i++) co.CA[i * 6 + j] = host_step(c, z, 0.0);
  }
}

static void build_eig(const FiltArg& c, EigArg& e) {
  double Pr[36];
  for (int s = 0; s < 3; s++) {
    double a1 = c.a1[s], a2 = c.a2[s];
    std::complex<double> disc = std::sqrt(std::complex<double>(a1 * a1 - 4.0 * a2, 0.0));
    std::complex<double> p = (-a1 + disc) / 2.0;
    if (p.imag() < 0) p = std::conj(p);
    std::complex<double> v[6] = {0, 0, 0, 0, 0, 0};
    v[2 * s] = 1.0;
    v[2 * s + 1] = a1 + p;
    std::complex<double> y = 1.0;
    for (int j = s + 1; j < 3; j++) {
      double b0j = c.b0[j], b1j = c.b1[j], b2j = c.b2[j];
      double a1j = c.a1[j], a2j = c.a2[j];
      std::complex<double> det = p * p + a1j * p + a2j;
      std::complex<double> r0 = (b1j - a1j * b0j) * y;
      std::complex<double> r1 = (b2j - a2j * b0j) * y;
      std::complex<double> z0 = (p * r0 + r1) / det;
      std::complex<double> z1 = ((p + a1j) * r1 - a2j * r0) / det;
      v[2 * j] = z0; v[2 * j + 1] = z1;
      y = b0j * y + z0;
    }
    for (int i = 0; i < 6; i++) {
      Pr[i * 6 + 2 * s]     = v[i].real();
      Pr[i * 6 + 2 * s + 1] = v[i].imag();
    }
    std::complex<double> lam = std::pow(p, CHUNK);
    e.lam_re[s] = lam.real(); e.lam_im[s] = lam.imag();
    std::complex<double> li = 1.0 / lam;
    e.lami_re[s] = li.real(); e.lami_im[s] = li.imag();
  }
  for (int i = 0; i < 36; i++) e.Pm[i] = Pr[i];
  double M[6][12];
  for (int i = 0; i < 6; i++)
    for (int j = 0; j < 6; j++) { M[i][j] = Pr[i * 6 + j]; M[i][6 + j] = (i == j) ? 1.0 : 0.0; }
  for (int col = 0; col < 6; col++) {
    int piv = col;
    for (int i = col + 1; i < 6; i++)
      if (std::fabs(M[i][col]) > std::fabs(M[piv][col])) piv = i;
    if (piv != col) for (int j = 0; j < 12; j++) std::swap(M[col][j], M[piv][j]);
    double d = M[col][col];
    for (int j = 0; j < 12; j++) M[col][j] /= d;
    for (int i = 0; i < 6; i++) if (i != col) {
      double f = M[i][col];
      for (int j = 0; j < 12; j++) M[i][j] -= f * M[col][j];
    }
  }
  for (int i = 0; i < 6; i++)
    for (int j = 0; j < 6; j++) e.Pinv[i * 6 + j] = M[i][6 + j];
  double zv[6];
  for (int s = 0; s < 3; s++) { zv[2 * s] = c.zi0[s]; zv[2 * s + 1] = c.zi1[s]; }
  for (int i = 0; i < 6; i++) {
    double sum = 0.0;
    for (int j = 0; j < 6; j++) sum += e.Pinv[i * 6 + j] * zv[j];
    e.czi[i] = sum;
  }
}

static double bessel_i0(double x) {
  double s = 1.0, t = 1.0;
  for (int k = 1; k < 64; k++) {
    double u = x / (2.0 * k);
    t *= u * u; s += t;
    if (t < 1e-18 * s) break;
  }
  return s;
}

static void design_fir(FirArg& fa) {
  double h[501];
  const double fc = 1.0 / 25.0;
  double denom = bessel_i0(5.0);
  double sum = 0.0;
  for (int nn = 0; nn < 501; nn++) {
    double m = nn - 250.0;
    double xx = fc * m;
    double snc = (nn == 250) ? 1.0 : std::sin(M_PI * xx) / (M_PI * xx);
    double r = (2.0 * nn) / 500.0 - 1.0;
    double w = bessel_i0(5.0 * std::sqrt(std::max(0.0, 1.0 - r * r))) / denom;
    h[nn] = fc * snc * w; sum += h[nn];
  }
  for (int nn = 0; nn < 25; nn++) fa.h[nn] = 0.0f;          // n_pre_pad = 25
  for (int nn = 0; nn < 501; nn++) fa.h[25 + nn] = (float)(h[nn] / sum * 16.0);
}

// ---------------- device helpers ----------------
__device__ inline double waveReduceSum(double v) {
  #pragma unroll
  for (int off = 32; off > 0; off >>= 1) v += __shfl_down(v, off, 64);
  return v;
}

__device__ inline void cpowf_int(float br, float bi, int n, float& rr_, float& ri_) {
  float rr = 1.f, ri = 0.f;
  while (n) {
    if (n & 1) { float t = rr * br - ri * bi; ri = rr * bi + ri * br; rr = t; }
    float t2 = br * br - bi * bi; bi = 2.f * br * bi; br = t2;
    n >>= 1;
  }
  rr_ = rr; ri_ = ri;
}

// ---------------- kernel 1: chansel + filtfilt + resample + norm (fused, f32) -
// Blocks [0,640): one row each, 512 threads, CHUNK=4 steps/thread — measured
// optimum of the chain-vs-scan tradeoff (CHUNK=8: 41.8us, CHUNK=4: ~30us,
// CHUNK=2: 73.9us). λ^±gk powers hoisted (computed once, used by both
// fwd/bwd scans). Blocks [640,680): PE table; block 679 zeroes out.
#define XR(t) xr[(t) + ((t) >> 5)]
#define YFS(t) yfs[(t) + ((t) >> 5)]
__global__ __launch_bounds__(512) void k_filt_resamp(const float* __restrict__ xin,
                                                     float* __restrict__ xn,
                                                     float* __restrict__ pe,
                                                     float* __restrict__ out,
                                                     FiltArg c, CorArg co, EigArg eg,
                                                     FirArg fa) {
  int bid = blockIdx.x;
  int gk = threadIdx.x;           // chunk id 0..511
  if (bid >= 640) {               // ---- PE-table + out-zero blocks ----
    int i = (bid - 640) * 512 + gk; // [0, 20480)
    int t = i >> 4, d = i & 15, j2 = d >> 1;
    double div = exp(-((double)(2 * j2)) * 0.5756462732485114); // ln(10000)/16
    double a = (double)t * div;
    pe[i] = (float)((d & 1) ? cos(a) : sin(a));
    if (bid == 679 && gk < 64) out[gk] = 0.f;
    return;
  }
  int r = (bid & 7) * 80 + (bid >> 3);   // bijective [0,640): XCD-local batches
  __shared__ float xd[2000];      // demeaned row, later reused for final output
  __shared__ float xr[2178];      // extended input seq (padded)
  __shared__ float yfs[2178];     // corrected forward output (padded, f32)
  __shared__ float hl[526];
  __shared__ float wtot[3][8][2]; // per-wave scan totals per section
  __shared__ double red[16];
  int lane = gk & 63;
  int wv = gk >> 6;               // 0..7
  int bb = r / 10, cc = r % 10;
  const int ch[10] = {126, 125, 48, 112, 67, 93, 10, 61, 39, 108};
  const float* xb = xin + (size_t)bb * 128 * 2000;

  for (int i = gk; i < 526; i += 512) hl[i] = fa.h[i];
  // demeaned row into LDS (identical arithmetic to the original chansel)
  for (int t = gk; t < 2000; t += 512) {
    float own = 0.f, ssum = 0.f;
    #pragma unroll
    for (int c2 = 0; c2 < 10; c2++) {
      float vv = xb[ch[c2] * 2000 + t];
      ssum += vv;
      if (c2 == cc) own = vv;
    }
    xd[t] = own - ssum * 0.1f;
  }
  __syncthreads();

  float x0f = xd[0], xlf = xd[1999];
  for (int t = gk; t < 2048; t += 512) {
    float v;
    if (t < 21)        v = 2.f * x0f - xd[21 - t];
    else if (t < 2021) v = xd[t - 21];
    else if (t < 2042) v = 2.f * xlf - xd[4019 - t];
    else               v = 0.f;
    XR(t) = v;
  }
  __syncthreads();

  float b0[3], b1[3], b2[3], a1[3], a2[3];
  #pragma unroll
  for (int s = 0; s < 3; s++) {
    b0[s] = (float)c.b0[s]; b1[s] = (float)c.b1[s]; b2[s] = (float)c.b2[s];
    a1[s] = (float)c.a1[s]; a2[s] = (float)c.a2[s];
  }
  // hoisted λ^gk and λ^-gk per section (used by BOTH eigscan calls)
  float lamk_re[3], lamk_im[3], lamik_re[3], lamik_im[3];
  #pragma unroll
  for (int s3 = 0; s3 < 3; s3++) {
    cpowf_int((float)eg.lam_re[s3], (float)eg.lam_im[s3], gk, lamk_re[s3], lamk_im[s3]);
    cpowf_int((float)eg.lami_re[s3], (float)eg.lami_im[s3], gk, lamik_re[s3], lamik_im[s3]);
  }

  auto step = [&](float* z, float v) -> float {
    #pragma unroll
    for (int s = 0; s < 3; s++) {
      float y = b0[s] * v + z[2 * s];
      z[2 * s]     = b1[s] * v - a1[s] * y + z[2 * s + 1];
      z[2 * s + 1] = b2[s] * v - a2[s] * y;
      v = y;
    }
    return v;
  };

  auto eigscan = [&](float seed, const float* F, float* zst) {
    float G[6];
    #pragma unroll
    for (int i = 0; i < 6; i++) {
      float s = 0.f;
      #pragma unroll
      for (int j = 0; j < 6; j++) s += (float)eg.Pinv[i * 6 + j] * F[j];
      G[i] = s;
    }
    float tre[3], tim[3], sre[3], sim[3];
    #pragma unroll
    for (int s3 = 0; s3 < 3; s3++) {
      float gre = G[2 * s3], gim = -G[2 * s3 + 1];
      float mre = lamik_re[s3], mim = lamik_im[s3];    // λ^{-gk} (hoisted)
      tre[s3] = mre * gre - mim * gim;
      tim[s3] = mre * gim + mim * gre;
      float pr = tre[s3], pi = tim[s3];
      #pragma unroll
      for (int off = 1; off < 64; off <<= 1) {
        float ore = __shfl_up(pr, off, 64);
        float oim = __shfl_up(pi, off, 64);
        pr += (lane >= off) ? ore : 0.f;
        pi += (lane >= off) ? oim : 0.f;
      }
      sre[s3] = pr; sim[s3] = pi;
      if (lane == 63) { wtot[s3][wv][0] = pr; wtot[s3][wv][1] = pi; }
    }
    __syncthreads();
    float coord[6];
    #pragma unroll
    for (int s3 = 0; s3 < 3; s3++) {
      float inc_re = sre[s3], inc_im = sim[s3];
      for (int w = 0; w < wv; w++) {      // wave-uniform trip count
        inc_re += wtot[s3][w][0];
        inc_im += wtot[s3][w][1];
      }
      float Sre = inc_re - tre[s3], Sim = inc_im - tim[s3];
      float c0re = seed * (float)eg.czi[2 * s3];
      float c0im = -seed * (float)eg.czi[2 * s3 + 1];
      float lkre = lamk_re[s3], lkim = lamk_im[s3];    // λ^{gk} (hoisted)
      float lamire = (float)eg.lami_re[s3], lamiim = (float)eg.lami_im[s3];
      float lm1re = lkre * lamire - lkim * lamiim;     // λ^{gk-1}
      float lm1im = lkre * lamiim + lkim * lamire;
      if (gk == 0) { lm1re = 0.f; lm1im = 0.f; }
      float cre = lkre * c0re - lkim * c0im + lm1re * Sre - lm1im * Sim;
      float cim = lkre * c0im + lkim * c0re + lm1re * Sim + lm1im * Sre;
      coord[2 * s3] = cre;
      coord[2 * s3 + 1] = -cim;
    }
    #pragma unroll
    for (int i = 0; i < 6; i++) {
      float s = 0.f;
      #pragma unroll
      for (int j = 0; j < 6; j++) s += (float)eg.Pm[i * 6 + j] * coord[j];
      zst[i] = s;
    }
  };

  int t0 = gk * CHUNK;
  float z[6], yreg[CHUNK], zst[6];

  #pragma unroll
  for (int i = 0; i < 6; i++) z[i] = 0.f;
  #pragma unroll
  for (int i = 0; i < CHUNK; i++) yreg[i] = step(z, XR(t0 + i));
  eigscan(XR(0), z, zst);
  #pragma unroll
  for (int i = 0; i < CHUNK; i++) {
    float corr = 0.f;
    #pragma unroll
    for (int j = 0; j < 6; j++) corr += (float)co.CA[i * 6 + j] * zst[j];
    YFS(t0 + i) = yreg[i] + corr;
  }
  __syncthreads();

  auto rin = [&](int j) -> float { return (j <= 2041) ? YFS(2041 - j) : 0.f; };
  float seedB = YFS(2041);
  #pragma unroll
  for (int i = 0; i < 6; i++) z[i] = 0.f;
  #pragma unroll
  for (int i = 0; i < CHUNK; i++) yreg[i] = step(z, rin(t0 + i));
  eigscan(seedB, z, zst);
  #pragma unroll
  for (int i = 0; i < CHUNK; i++) {
    int j = t0 + i;
    if (j >= 21 && j <= 2020) {
      float corr = 0.f;
      #pragma unroll
      for (int jj = 0; jj < 6; jj++) corr += (float)co.CA[i * 6 + jj] * zst[jj];
      xd[2020 - j] = yreg[i] + corr;        // reversed + trimmed -> LDS
    }
  }
  __syncthreads();

  // ---- polyphase resample + tanh + per-row normalize (from LDS xd) ----
  float vals[3];
  #pragma unroll
  for (int kk = 0; kk < 3; kk++) {
    int o = gk + kk * 512;                    // 1280 outputs per row
    vals[kk] = 0.f;
    if (o < 1280) {
      int P = 25 * (o + 11);
      int phase = P & 15;
      float acc = 0.f;
      for (int m = phase; m <= 525; m += 16) {
        int idx = (P - m) >> 4;
        if (idx >= 0 && idx < 2000) acc += hl[m] * xd[idx];
      }
      vals[kk] = tanhf(acc);
    }
  }
  double s = 0.0, ss = 0.0;
  #pragma unroll
  for (int kk = 0; kk < 3; kk++) {
    s += (double)vals[kk]; ss += (double)vals[kk] * (double)vals[kk];
  }
  s = waveReduceSum(s); ss = waveReduceSum(ss);
  if (lane == 0) { red[wv] = s; red[8 + wv] = ss; }
  __syncthreads();
  double S = 0.0, SS = 0.0;
  #pragma unroll
  for (int w = 0; w < 8; w++) { S += red[w]; SS += red[8 + w]; }
  double mean = S / 1280.0;
  double var = (SS - 1280.0 * mean * mean) / 1279.0;
  double sd = fmax(sqrt(fmax(var, 0.0)), 1e-6);
  float fmean = (float)mean, finv = (float)(1.0 / sd);
  #pragma unroll
  for (int kk = 0; kk < 3; kk++) {
    int o = gk + kk * 512;
    if (o < 1280)
      xn[(size_t)r * 1280 + o] = (vals[kk] - fmean) * finv;
  }
}

// ---------------- kernel 2: conv1d + relu + LN + PE + QKV (Q,K,V emitted f16) -
__global__ __launch_bounds__(256) void k_conv_ln_pe_qkv(const float* __restrict__ xn,
    const float* __restrict__ cw, const float* __restrict__ cb,
    const float* __restrict__ g0, const float* __restrict__ bt0,
    const float* __restrict__ wqkv, const float* __restrict__ bqkv,
    const float* __restrict__ pe,
    float* __restrict__ x0, _Float16* __restrict__ Qh,
    _Float16* __restrict__ Kp, _Float16* __restrict__ Vt_g) {
  __shared__ float w[480], bias[16], gg[16], gb[16];
  __shared__ float wq[768], bq[48];
  for (int i = threadIdx.x; i < 480; i += 256) w[i] = cw[i];
  for (int i = threadIdx.x; i < 768; i += 256) wq[i] = wqkv[i];
  if (threadIdx.x < 16) {
    bias[threadIdx.x] = cb[threadIdx.x];
    gg[threadIdx.x] = g0[threadIdx.x];
    gb[threadIdx.x] = bt0[threadIdx.x];
  }
  if (threadIdx.x < 48) bq[threadIdx.x] = bqkv[threadIdx.x];
  __syncthreads();
  int idx = blockIdx.x * 256 + threadIdx.x;
  int b = idx / 1280, t = idx % 1280;
  const float* xb = xn + (size_t)b * 10 * 1280;
  float in[10][3];
  #pragma unroll
  for (int i = 0; i < 10; i++)
    #pragma unroll
    for (int k = 0; k < 3; k++) {
      int tt = t - 1 + k;
      in[i][k] = (tt >= 0 && tt < 1280) ? xb[i * 1280 + tt] : 0.f;
    }
  float o[16];
  #pragma unroll
  for (int oc = 0; oc < 16; oc++) {
    float a = bias[oc];
    #pragma unroll
    for (int i = 0; i < 10; i++)
      #pragma unroll
      for (int k = 0; k < 3; k++) a += in[i][k] * w[oc * 30 + i * 3 + k];
    o[oc] = fmaxf(a, 0.f);
  }
  float mu = 0.f;
  #pragma unroll
  for (int d = 0; d < 16; d++) mu += o[d];
  mu *= (1.f / 16.f);
  float var = 0.f;
  #pragma unroll
  for (int d = 0; d < 16; d++) { float dd = o[d] - mu; var += dd * dd; }
  var *= (1.f / 16.f);
  float inv = 1.f / sqrtf(var + 1e-5f);
  float xv[16];
  float* outp = x0 + (size_t)idx * 16;
  const float* pep = pe + t * 16;
  #pragma unroll
  for (int d = 0; d < 16; d++) {
    xv[d] = (o[d] - mu) * inv * gg[d] + gb[d] + pep[d];
    outp[d] = xv[d];
  }
  _Float16* qh = Qh + (size_t)idx * 16;
  #pragma unroll
  for (int j = 0; j < 16; j++) {
    float a = bq[j];
    #pragma unroll
    for (int d = 0; d < 16; d++) a += xv[d] * wq[j * 16 + d];
    qh[j] = (_Float16)(0.36067376f * a);   // 0.25 * log2(e)
  }
  {
    _Float16* kp = Kp + (size_t)idx * 16;
    #pragma unroll
    for (int j = 0; j < 16; j++) {
      float a = bq[16 + j];
      #pragma unroll
      for (int d = 0; d < 16; d++) a += xv[d] * wq[(16 + j) * 16 + d];
      kp[j] = (_Float16)a;
    }
  }
  {
    _Float16* vt = Vt_g + (size_t)b * 16 * 1280 + t;
    #pragma unroll
    for (int j = 0; j < 16; j++) {
      float a = bq[32 + j];
      #pragma unroll
      for (int d = 0; d < 16; d++) a += xv[d] * wq[(32 + j) * 16 + d];
      vt[j * 1280] = (_Float16)a;
    }
  }
}

// ---------------- kernel 3: MFMA attention + combine + pool (fused) -----------
// r9 zero-shuffle configuration (verified): key-relabeled PV (P-slot/V-slot
// agree per lane), MFMA-ones denominator, XCD swizzle, 128-key dbuf tiles.
#define SHIFT2 17.3123404907f   /* 12 * log2(e) */
__global__ __launch_bounds__(256) void k_attn_combine(const _Float16* __restrict__ Qh,
    const _Float16* __restrict__ Kp, const _Float16* __restrict__ Vt_g,
    const float* __restrict__ x0,
    const float* __restrict__ wo, const float* __restrict__ bo,
    const float* __restrict__ w1, const float* __restrict__ b1,
    const float* __restrict__ w2, const float* __restrict__ b2,
    const float* __restrict__ g1, const float* __restrict__ bb1,
    const float* __restrict__ g2, const float* __restrict__ bb2,
    const float* __restrict__ wfc, const float* __restrict__ bfc,
    float* __restrict__ out) {
  __shared__ __align__(16) _Float16 Ks[2][128 * 16];   // [buf][key][d]
  __shared__ __align__(16) _Float16 Vt[2][16 * 136];   // [buf][d][key+8pad]
  __shared__ float Aly[64][17];                        // normalized attn rows
  __shared__ float swo[256], sw1[512], sw2[512];
  __shared__ float sbo[16], sb1[32], sb2[16], sg1[16], sbb1[16], sg2[16], sbb2[16];
  __shared__ float swf[16];
  int tid = threadIdx.x;
  // XCD swizzle: bid&7 = XCD (round-robin). Keep a batch on one XCD.
  int bid = blockIdx.x;
  int jj  = bid >> 3;
  int b   = (bid & 7) + 8 * (jj & 7);   // [0,64)
  int rg  = jj >> 3;                    // [0,20)
  int wv = tid >> 6;
  int lane = tid & 63;
  int col = lane & 15;
  int quad = lane >> 4;
  size_t base = (size_t)b * 1280;
  int row0 = rg * 64 + wv * 16;

  // stage combine weights (consumed after a barrier)
  swo[tid] = wo[tid];
  for (int i = tid; i < 512; i += 256) { sw1[i] = w1[i]; sw2[i] = w2[i]; }
  if (tid < 16) {
    sbo[tid] = bo[tid]; sb2[tid] = b2[tid];
    sg1[tid] = g1[tid]; sbb1[tid] = bb1[tid];
    sg2[tid] = g2[tid]; sbb2[tid] = bb2[tid];
    swf[tid] = wfc[tid];
  }
  if (tid < 32) sb1[tid] = b1[tid];

  // Q fragment (B operand, k=quad*8+j; quads 2-3 zero == K dims 16..31 zero)
  f16x8 qf;
  #pragma unroll
  for (int j = 0; j < 8; j++) qf[j] = (_Float16)0.f;
  if (quad < 2)
    qf = *(const f16x8*)(Qh + (base + row0 + col) * 16 + quad * 8);

  f16x8 ones;
  #pragma unroll
  for (int j = 0; j < 8; j++) ones[j] = (_Float16)1.f;

  const _Float16* kp_b = Kp + base * 16;
  const _Float16* vt_b = Vt_g + (size_t)b * 16 * 1280;

  // staging roles: Ks by all 256 (16B each), Vt by all 256 (16B each)
  int srow = tid >> 1, shalf = tid & 1;      // Ks: key row, 8-f16 half
  int sd = tid >> 4, sseg = tid & 15;        // Vt: d row, 8-key segment

  // prologue: tile 0 -> buf 0
  {
    f16x8 kreg = *(const f16x8*)(kp_b + (size_t)srow * 16 + shalf * 8);
    f16x8 vreg = *(const f16x8*)(vt_b + (size_t)sd * 1280 + sseg * 8);
    *(f16x8*)&Ks[0][srow * 16 + shalf * 8] = kreg;
    *(f16x8*)&Vt[0][sd * 136 + sseg * 8] = vreg;
  }

  f32x4 oacc = {0.f, 0.f, 0.f, 0.f};
  f32x4 lacc = {0.f, 0.f, 0.f, 0.f};

  union U32H2 { fp16x2 h; unsigned int u; };
  union PFU { unsigned int u[4]; f16x8 v; };
  union VFU { unsigned long long d[2]; f16x8 v; };

  for (int s = 0; s < 10; s++) {
    int cur = s & 1;
    f16x8 kreg, vreg;
    if (s < 9) {                     // issue next-tile global loads early
      kreg = *(const f16x8*)(kp_b + (size_t)((s + 1) * 128 + srow) * 16 + shalf * 8);
      vreg = *(const f16x8*)(vt_b + (size_t)sd * 1280 + (s + 1) * 128 + sseg * 8);
    }
    __syncthreads();                 // buf[cur] staging complete
    const _Float16* ks = &Ks[cur][0];
    const _Float16* vt = &Vt[cur][0];

    // Phase A: QK + exp for all 8 sub-tiles (max ILP across exp chains)
    unsigned int pp[8][2];
    #pragma unroll
    for (int st = 0; st < 8; st++) {
      f16x8 af;
      #pragma unroll
      for (int j = 0; j < 8; j++) af[j] = (_Float16)0.f;
      if (quad < 2)
        af = *(const f16x8*)&ks[(st * 16 + col) * 16 + quad * 8];
      f32x4 sf = {-SHIFT2, -SHIFT2, -SHIFT2, -SHIFT2};
      sf = __builtin_amdgcn_mfma_f32_16x16x32_f16(af, qf, sf, 0, 0, 0);
      float e0 = __builtin_amdgcn_exp2f(sf[0]);
      float e1 = __builtin_amdgcn_exp2f(sf[1]);
      float e2 = __builtin_amdgcn_exp2f(sf[2]);
      float e3 = __builtin_amdgcn_exp2f(sf[3]);
      U32H2 t0, t1;
      t0.h = __builtin_amdgcn_cvt_pkrtz(e0, e1);
      t1.h = __builtin_amdgcn_cvt_pkrtz(e2, e3);
      pp[st][0] = t0.u;              // keys st*16 + quad*4 + {0,1}, q=col
      pp[st][1] = t1.u;              // keys st*16 + quad*4 + {2,3}
    }

    // Phase B: zero-shuffle PV. A-slot 8*quad+j holds the lane's own exp
    // values (keys c*32+{4q..4q+3, 16+4q..16+4q+3}); V read at same keys.
    #pragma unroll
    for (int c = 0; c < 4; c++) {
      PFU pu;
      pu.u[0] = pp[2 * c][0];          // keys c*32 + 4*quad + {0,1}
      pu.u[1] = pp[2 * c][1];          // keys c*32 + 4*quad + {2,3}
      pu.u[2] = pp[2 * c + 1][0];      // keys c*32 + 16 + 4*quad + {0,1}
      pu.u[3] = pp[2 * c + 1][1];      // keys c*32 + 16 + 4*quad + {2,3}
      f16x8 pf = pu.v;
      VFU vu;
      vu.d[0] = *(const unsigned long long*)&vt[col * 136 + c * 32 + quad * 4];
      vu.d[1] = *(const unsigned long long*)&vt[col * 136 + c * 32 + 16 + quad * 4];
      f16x8 vf = vu.v;
      oacc = __builtin_amdgcn_mfma_f32_16x16x32_f16(pf, vf, oacc, 0, 0, 0);
      lacc = __builtin_amdgcn_mfma_f32_16x16x32_f16(pf, ones, lacc, 0, 0, 0);
    }
    if (s < 9) {                     // write next tile to the other buffer
      *(f16x8*)&Ks[cur ^ 1][srow * 16 + shalf * 8] = kreg;
      *(f16x8*)&Vt[cur ^ 1][sd * 136 + sseg * 8] = vreg;
    }
  }

  // lacc[r] = l for q-row quad*4+r (identical across cols) -> normalize here
  #pragma unroll
  for (int r = 0; r < 4; r++)
    Aly[wv * 16 + quad * 4 + r][col] = oacc[r] / lacc[r];
  __syncthreads();

  // ---- epilogue: wave 0, one thread per row ----
  if (tid < 64) {
    int grow = rg * 64 + tid;                 // row within batch
    size_t goff = (base + grow) * 16;
    float a[16];
    #pragma unroll
    for (int d = 0; d < 16; d++) a[d] = Aly[tid][d];
    float h[16];
    const float* xr = x0 + goff;
    #pragma unroll
    for (int d = 0; d < 16; d++) {
      float o = sbo[d];
      #pragma unroll
      for (int e = 0; e < 16; e++) o += a[e] * swo[d * 16 + e];
      h[d] = xr[d] + o;
    }
    float mu = 0.f;
    #pragma unroll
    for (int d = 0; d < 16; d++) mu += h[d];
    mu *= (1.f / 16.f);
    float var = 0.f;
    #pragma unroll
    for (int d = 0; d < 16; d++) { float dd = h[d] - mu; var += dd * dd; }
    var *= (1.f / 16.f);
    float inv = 1.f / sqrtf(var + 1e-5f);
    float x1[16];
    #pragma unroll
    for (int d = 0; d < 16; d++) x1[d] = (h[d] - mu) * inv * sg1[d] + sbb1[d];
    float t1[32];
    #pragma unroll
    for (int j = 0; j < 32; j++) {
      float u = sb1[j];
      #pragma unroll
      for (int d = 0; d < 16; d++) u += x1[d] * sw1[j * 16 + d];
      t1[j] = fmaxf(u, 0.f);
    }
    float h2[16];
    #pragma unroll
    for (int d = 0; d < 16; d++) {
      float u = sb2[d];
      #pragma unroll
      for (int j = 0; j < 32; j++) u += t1[j] * sw2[d * 32 + j];
      h2[d] = x1[d] + u;
    }
    mu = 0.f;
    #pragma unroll
    for (int d = 0; d < 16; d++) mu += h2[d];
    mu *= (1.f / 16.f);
    var = 0.f;
    #pragma unroll
    for (int d = 0; d < 16; d++) { float dd = h2[d] - mu; var += dd * dd; }
    var *= (1.f / 16.f);
    inv = 1.f / sqrtf(var + 1e-5f);
    float pv = 0.f;
    #pragma unroll
    for (int d = 0; d < 16; d++)
      pv += ((h2[d] - mu) * inv * sg2[d] + sbb2[d]) * swf[d];
    double part = waveReduceSum((double)pv);
    if (tid == 0) {
      float add = (float)(part / 1280.0);
      if (rg == 0) add += bfc[0];           // once per batch (swizzled ids!)
      atomicAdd(&out[b], add);
    }
  }
}

// ---------------- launch ------------------------------------------------------
extern "C" void kernel_launch(void* const* d_in, const int* in_sizes, int n_in,
                              void* d_out, int out_size, void* d_ws, size_t ws_size,
                              hipStream_t stream) {
  const float* x    = (const float*)d_in[0];
  const float* cw   = (const float*)d_in[1];
  const float* cb   = (const float*)d_in[2];
  const float* g0   = (const float*)d_in[3];
  const float* bt0  = (const float*)d_in[4];
  const float* wqkv = (const float*)d_in[5];
  const float* bqkv = (const float*)d_in[6];
  const float* wo   = (const float*)d_in[7];
  const float* bo   = (const float*)d_in[8];
  const float* w1   = (const float*)d_in[9];
  const float* b1   = (const float*)d_in[10];
  const float* w2   = (const float*)d_in[11];
  const float* b2   = (const float*)d_in[12];
  const float* g1   = (const float*)d_in[13];
  const float* bb1  = (const float*)d_in[14];
  const float* g2   = (const float*)d_in[15];
  const float* bb2  = (const float*)d_in[16];
  const float* wfc  = (const float*)d_in[17];
  const float* bfc  = (const float*)d_in[18];
  float* out = (float*)d_out;

  float* ws = (float*)d_ws;
  float* xs = ws;                       // (dead; layout kept stable)
  float* y1 = xs + 1280000;             // spacer (dead)
  float* xn = y1 + 1306880;             // 640*1280   =   819,200
  float* x0 = xn + 819200;              // 64*1280*16 = 1,310,720
  _Float16* Qh   = (_Float16*)(x0 + 1310720);     // 64*1280*16 f16 = 655,360 floats
  _Float16* Kp   = (_Float16*)(x0 + 1310720 + 655360);
  _Float16* Vt_g = (_Float16*)(x0 + 1310720 + 2 * 655360);
  float* pe = x0 + 1310720 + 3 * 655360;          // 1280*16 = 20,480 (total ~27 MB)

  FiltArg fc; CorArg co; EigArg eg; FirArg fa;
  build_filt(fc, co);
  build_eig(fc, eg);
  design_fir(fa);

  k_filt_resamp<<<680, 512, 0, stream>>>(x, xn, pe, out, fc, co, eg, fa);
  k_conv_ln_pe_qkv<<<320, 256, 0, stream>>>(xn, cw, cb, g0, bt0, wqkv, bqkv,
                                            pe, x0, Qh, Kp, Vt_g);
  k_attn_combine<<<1280, 256, 0, stream>>>(Qh, Kp, Vt_g, x0, wo, bo, w1, b1,
                                           w2, b2, g1, bb1, g2, bb2, wfc, bfc,
                                           out);
}